// Round 2
// baseline (895.007 us; speedup 1.0000x reference)
//
#include <hip/hip_runtime.h>

typedef short bf16x8 __attribute__((ext_vector_type(8)));
typedef float f32x4  __attribute__((ext_vector_type(4)));

#define AS1 __attribute__((address_space(1)))
#define AS3 __attribute__((address_space(3)))

__device__ __forceinline__ void gload16(const void* g, void* l) {
  __builtin_amdgcn_global_load_lds((const AS1 void*)g, (AS3 void*)l, 16, 0, 0);
}

__device__ __forceinline__ short f2bf(float f) {
  union { float fv; unsigned u; } v; v.fv = f;
  unsigned r = v.u + 0x7fffu + ((v.u >> 16) & 1u);
  return (short)(r >> 16);
}

// in-place 16-lane max reduction step via ds_swizzle (xor pattern, 1 instr)
#define MAXSTEP(x, IMM) { int t_ = __builtin_amdgcn_ds_swizzle(__float_as_int(x), IMM); \
                          x = fmaxf(x, __int_as_float(t_)); }

// ---------------- cast x (fp32 -> bf16), 4 elems/thread ----------------
__global__ void cast_x_kernel(const float* __restrict__ x, short* __restrict__ xb, long n4) {
  long i = (long)blockIdx.x * 256 + threadIdx.x;
  if (i < n4) {
    float4 v = ((const float4*)x)[i];
    short4 s;
    s.x = f2bf(v.x); s.y = f2bf(v.y); s.z = f2bf(v.z); s.w = f2bf(v.w);
    ((short4*)xb)[i] = s;
  }
}

// ---------------- weight prep ----------------
__global__ void prep_kernel(const float* __restrict__ left_w, const float* __restrict__ diag,
                            const float* __restrict__ right_w,
                            short* __restrict__ LT, short* __restrict__ WT) {
  long idx = (long)blockIdx.x * 256 + threadIdx.x;
  const long LTN = 4L * 128 * 2048;
  const long WTN = 4L * 16 * 128 * 256;
  if (idx < LTN) {
    LT[idx] = f2bf(left_w[idx]);
  } else if (idx < LTN + WTN) {
    long j = idx - LTN;
    int d = (int)(j & 255);
    long rest = j >> 8;
    int e = (int)(rest & 127);
    long gi = rest >> 7;
    int i = (int)(gi >> 4), n = (int)(gi & 15);
    float v;
    if (d < 128) v = diag[(gi * 128 + d) * 128 + e];
    else         v = right_w[((long)i * 2048 + n * 128 + e) * 128 + (d - 128)];
    WT[j] = f2bf(v);
  }
}

// ---------------- 128x128-tile GEMM (XOR-swizzled LDS): C = A @ BT^T ----------------
__global__ __launch_bounds__(256) void gemm_bt(const short* __restrict__ A, const short* __restrict__ BT,
                                               short* __restrict__ C, int M, int N, int K) {
  __shared__ __align__(16) short As[128 * 64];
  __shared__ __align__(16) short Bs[128 * 64];
  int tid = threadIdx.x, w = tid >> 6, lane = tid & 63;
  int m0 = blockIdx.x * 128, n0 = blockIdx.y * 128;
  int wm = (w >> 1) * 64, wn = (w & 1) * 64;
  int quad = lane >> 4, l16 = lane & 15;
  int srow = lane >> 3;
  int schunk = ((lane & 7) ^ srow) * 8;   // XOR-swizzled source chunk
  f32x4 acc[4][4] = {};
  for (int k0 = 0; k0 < K; k0 += 64) {
    for (int p = 0; p < 4; ++p) {
      int r = p * 32 + w * 8 + srow;
      gload16(&A[(long)(m0 + r) * K + k0 + schunk], &As[(p * 32 + w * 8) * 64]);
      gload16(&BT[(long)(n0 + r) * K + k0 + schunk], &Bs[(p * 32 + w * 8) * 64]);
    }
    __syncthreads();
#pragma unroll
    for (int kk = 0; kk < 2; ++kk) {
      int c = (((kk * 4 + quad) ^ (l16 & 7)) * 8);
      bf16x8 a[4], b[4];
#pragma unroll
      for (int t = 0; t < 4; ++t) a[t] = *(const bf16x8*)&As[(wm + t * 16 + l16) * 64 + c];
#pragma unroll
      for (int t = 0; t < 4; ++t) b[t] = *(const bf16x8*)&Bs[(wn + t * 16 + l16) * 64 + c];
#pragma unroll
      for (int mt = 0; mt < 4; ++mt)
#pragma unroll
        for (int nt = 0; nt < 4; ++nt)
          acc[mt][nt] = __builtin_amdgcn_mfma_f32_16x16x32_bf16(a[mt], b[nt], acc[mt][nt], 0, 0, 0);
    }
    __syncthreads();
  }
#pragma unroll
  for (int mt = 0; mt < 4; ++mt)
#pragma unroll
    for (int nt = 0; nt < 4; ++nt)
#pragma unroll
      for (int r = 0; r < 4; ++r) {
        int m = m0 + wm + mt * 16 + quad * 4 + r;
        int n = n0 + wn + nt * 16 + l16;
        C[(long)m * N + n] = f2bf(acc[mt][nt][r]);
      }
}

// ---------------- grouped lori GEMM (XOR-swizzled LDS) ----------------
__global__ __launch_bounds__(256) void lori_gemm(const short* __restrict__ tok, const short* __restrict__ rnk,
                                                 int rstride, const short* __restrict__ WT,
                                                 const float* __restrict__ rb, const float* __restrict__ bp,
                                                 int i_base, short* __restrict__ qb, short* __restrict__ kb,
                                                 short* __restrict__ vT, float* __restrict__ out) {
  __shared__ __align__(16) short As[128 * 64];
  __shared__ __align__(16) short Bs[128 * 64];
  int tid = threadIdx.x, w = tid >> 6, lane = tid & 63;
  int i = i_base + (blockIdx.y >> 4);
  int n = blockIdx.y & 15;
  int t0 = blockIdx.x * 128;
  int co = (i < 3) ? i * 128 : 0;
  const short* WTn = WT + (long)(i * 16 + n) * 128 * 256;
  int wm = (w >> 1) * 64, wn = (w & 1) * 64;
  int quad = lane >> 4, l16 = lane & 15;
  int srow = lane >> 3;
  int schunk = ((lane & 7) ^ srow) * 8;
  f32x4 acc[4][4] = {};
#pragma unroll
  for (int kt = 0; kt < 4; ++kt) {
    for (int p = 0; p < 4; ++p) {
      int r = p * 32 + w * 8 + srow;
      const short* ga;
      if (kt < 2) ga = &tok[(long)(t0 + r) * 2048 + n * 128 + kt * 64 + schunk];
      else        ga = &rnk[(long)(t0 + r) * rstride + co + (kt - 2) * 64 + schunk];
      gload16(ga, &As[(p * 32 + w * 8) * 64]);
      gload16(&WTn[r * 256 + kt * 64 + schunk], &Bs[(p * 32 + w * 8) * 64]);
    }
    __syncthreads();
#pragma unroll
    for (int kk = 0; kk < 2; ++kk) {
      int c = (((kk * 4 + quad) ^ (l16 & 7)) * 8);
      bf16x8 a[4], b[4];
#pragma unroll
      for (int t = 0; t < 4; ++t) a[t] = *(const bf16x8*)&As[(wm + t * 16 + l16) * 64 + c];
#pragma unroll
      for (int t = 0; t < 4; ++t) b[t] = *(const bf16x8*)&Bs[(wn + t * 16 + l16) * 64 + c];
#pragma unroll
      for (int mt = 0; mt < 4; ++mt)
#pragma unroll
        for (int nt = 0; nt < 4; ++nt)
          acc[mt][nt] = __builtin_amdgcn_mfma_f32_16x16x32_bf16(a[mt], b[nt], acc[mt][nt], 0, 0, 0);
    }
    __syncthreads();
  }
  int b = t0 >> 11;
  int tl0 = t0 & 2047;
  const float QSC = 0.08838834764831845f * 1.4426950408889634f;  // 1/sqrt(128) * log2(e)
#pragma unroll
  for (int mt = 0; mt < 4; ++mt) {
#pragma unroll
    for (int nt = 0; nt < 4; ++nt) {
      int e = wn + nt * 16 + l16;
      int c = n * 128 + e;
      float bias = rb[i * 2048 + c] + bp[i * 2048 + c];
      int tl = tl0 + wm + mt * 16 + quad * 4;
      if (i == 0) {
#pragma unroll
        for (int r = 0; r < 4; ++r)
          qb[((long)(b * 16 + n) * 2048 + tl + r) * 128 + e] = f2bf((acc[mt][nt][r] + bias) * QSC);
      } else if (i == 1) {
#pragma unroll
        for (int r = 0; r < 4; ++r)
          kb[((long)(b * 16 + n) * 2048 + tl + r) * 128 + e] = f2bf(acc[mt][nt][r] + bias);
      } else if (i == 2) {
        short4 s4;
        s4.x = f2bf(acc[mt][nt][0] + bias);
        s4.y = f2bf(acc[mt][nt][1] + bias);
        s4.z = f2bf(acc[mt][nt][2] + bias);
        s4.w = f2bf(acc[mt][nt][3] + bias);
        *(short4*)&vT[((long)(b * 16 + n) * 128 + e) * 2048 + tl] = s4;
      } else {
#pragma unroll
        for (int r = 0; r < 4; ++r)
          out[(long)(t0 + wm + mt * 16 + quad * 4 + r) * 2048 + c] = acc[mt][nt][r] + bias;
      }
    }
  }
}

// ---------------- flash attention v2: 128-row Q tile, swizzled LDS, MFMA row-sums ----------------
// qb,kb: [bh][t][d] bf16 (q pre-scaled by log2e/sqrt(128)); vT: [bh][d][t]; y: [b][t][h*128+d]
__global__ __launch_bounds__(256, 3) void attn_kernel(const short* __restrict__ qb, const short* __restrict__ kb,
                                                      const short* __restrict__ vT, short* __restrict__ y) {
  __shared__ __align__(16) short ks[64 * 128];   // K tile, 16-chunk XOR swizzle per row
  __shared__ __align__(16) short vs[128 * 64];   // V^T tile, 8-chunk XOR swizzle per row
  __shared__ __align__(16) short ps[4][32 * 64]; // P per wave, 8-chunk XOR swizzle per row
  int tid = threadIdx.x, w = tid >> 6, lane = tid & 63;
  int bh = blockIdx.y, b = bh >> 4, h = bh & 15;
  int qt = (gridDim.x - 1) - blockIdx.x;  // reversed: longest blocks dispatched first
  int quad = lane >> 4, l16 = lane & 15;

  // Q fragments direct global->VGPR (A-layout): rows w*32 + mt*16 + l16
  bf16x8 aq[2][4];
#pragma unroll
  for (int mt = 0; mt < 2; ++mt)
#pragma unroll
    for (int kk = 0; kk < 4; ++kk)
      aq[mt][kk] = *(const bf16x8*)&qb[((long)bh * 2048 + qt * 128 + w * 32 + mt * 16 + l16) * 128 + kk * 32 + quad * 8];

  f32x4 O[2][8] = {};
  f32x4 Lacc[2] = {};
  f32x4 mst[2];
#pragma unroll
  for (int mt = 0; mt < 2; ++mt) mst[mt] = f32x4{-3.0e38f, -3.0e38f, -3.0e38f, -3.0e38f};
  const bf16x8 ones = {(short)0x3F80, (short)0x3F80, (short)0x3F80, (short)0x3F80,
                       (short)0x3F80, (short)0x3F80, (short)0x3F80, (short)0x3F80};
  short* psw = &ps[w][0];

  // staging lane constants
  int kq = lane >> 4;                       // 0..3
  int kchunk = l16 ^ (w * 4 + kq);          // row&15 = w*4+kq
  int vrow8 = lane >> 3;                    // 0..7
  int vchunk = (lane & 7) ^ vrow8;          // row&7 = vrow8

  int jmax = 2 * qt + 1;
  for (int jt = 0; jt <= jmax; ++jt) {
    for (int p = 0; p < 4; ++p) {
      int r = p * 16 + w * 4 + kq;
      gload16(&kb[((long)bh * 2048 + jt * 64 + r) * 128 + kchunk * 8], &ks[(p * 16 + w * 4) * 128]);
      int r2 = p * 32 + w * 8 + vrow8;
      gload16(&vT[((long)bh * 128 + r2) * 2048 + jt * 64 + vchunk * 8], &vs[(p * 32 + w * 8) * 64]);
    }
    __syncthreads();

    bool active = !(jt == jmax && w < 2);   // waves 0,1 fully masked on the last diagonal sub-tile
    if (active) {
      // S = Q @ K^T  (wave: 32 rows x 64 keys)
      f32x4 s[2][4] = {};
#pragma unroll
      for (int nt = 0; nt < 4; ++nt)
#pragma unroll
        for (int kk = 0; kk < 4; ++kk) {
          bf16x8 bk = *(const bf16x8*)&ks[(nt * 16 + l16) * 128 + (((kk * 4 + quad) ^ l16) * 8)];
          s[0][nt] = __builtin_amdgcn_mfma_f32_16x16x32_bf16(aq[0][kk], bk, s[0][nt], 0, 0, 0);
          s[1][nt] = __builtin_amdgcn_mfma_f32_16x16x32_bf16(aq[1][kk], bk, s[1][nt], 0, 0, 0);
        }
      if (jt >= 2 * qt) {
#pragma unroll
        for (int mt = 0; mt < 2; ++mt)
#pragma unroll
          for (int nt = 0; nt < 4; ++nt) {
            int key = jt * 64 + nt * 16 + l16;
#pragma unroll
            for (int r = 0; r < 4; ++r) {
              int rowg = qt * 128 + w * 32 + mt * 16 + quad * 4 + r;
              if (key > rowg) s[mt][nt][r] = -3.0e38f;
            }
          }
      }
#pragma unroll
      for (int mt = 0; mt < 2; ++mt) {
        // running max + rescale factor (base-2 domain)
        f32x4 alv;
#pragma unroll
        for (int r = 0; r < 4; ++r) {
          float mx = fmaxf(fmaxf(s[mt][0][r], s[mt][1][r]), fmaxf(s[mt][2][r], s[mt][3][r]));
          MAXSTEP(mx, 0x041F); MAXSTEP(mx, 0x081F); MAXSTEP(mx, 0x101F); MAXSTEP(mx, 0x201F);
          float nm = fmaxf(mst[mt][r], mx);
          alv[r] = __builtin_amdgcn_exp2f(mst[mt][r] - nm);
          mst[mt][r] = nm;
        }
        Lacc[mt] *= alv;
#pragma unroll
        for (int dt = 0; dt < 8; ++dt) O[mt][dt] *= alv;
        // P = exp2(S - m), write to swizzled LDS (C-layout -> A-layout)
#pragma unroll
        for (int nt = 0; nt < 4; ++nt)
#pragma unroll
          for (int r = 0; r < 4; ++r) {
            float p = __builtin_amdgcn_exp2f(s[mt][nt][r] - mst[mt][r]);
            int row = mt * 16 + quad * 4 + r;
            int cw = (nt * 2 + (l16 >> 3)) ^ (row & 7);
            psw[row * 64 + cw * 8 + (l16 & 7)] = f2bf(p);
          }
        // O += P @ V ; Lacc += P @ 1
#pragma unroll
        for (int kk = 0; kk < 2; ++kk) {
          bf16x8 ap = *(const bf16x8*)&psw[(mt * 16 + l16) * 64 + (((kk * 4 + quad) ^ (l16 & 7)) * 8)];
#pragma unroll
          for (int dt = 0; dt < 8; ++dt) {
            bf16x8 bv = *(const bf16x8*)&vs[(dt * 16 + l16) * 64 + (((kk * 4 + quad) ^ (l16 & 7)) * 8)];
            O[mt][dt] = __builtin_amdgcn_mfma_f32_16x16x32_bf16(ap, bv, O[mt][dt], 0, 0, 0);
          }
          Lacc[mt] = __builtin_amdgcn_mfma_f32_16x16x32_bf16(ap, ones, Lacc[mt], 0, 0, 0);
        }
      }
    }
    __syncthreads();
  }
  // epilogue: y = O / l
#pragma unroll
  for (int mt = 0; mt < 2; ++mt) {
    f32x4 inv;
#pragma unroll
    for (int r = 0; r < 4; ++r) inv[r] = __builtin_amdgcn_rcpf(Lacc[mt][r]);
#pragma unroll
    for (int dt = 0; dt < 8; ++dt)
#pragma unroll
      for (int r = 0; r < 4; ++r) {
        int t = qt * 128 + w * 32 + mt * 16 + quad * 4 + r;
        y[((long)(b * 2048 + t)) * 2048 + h * 128 + dt * 16 + l16] = f2bf(O[mt][dt][r] * inv[r]);
      }
  }
}

extern "C" void kernel_launch(void* const* d_in, const int* in_sizes, int n_in,
                              void* d_out, int out_size, void* d_ws, size_t ws_size,
                              hipStream_t stream) {
  const float* x       = (const float*)d_in[0];
  const float* diag    = (const float*)d_in[1];
  const float* left_w  = (const float*)d_in[2];
  const float* right_w = (const float*)d_in[3];
  const float* right_b = (const float*)d_in[4];
  const float* bias_p  = (const float*)d_in[5];
  float* out = (float*)d_out;

  char* ws = (char*)d_ws;
  short* xb = (short*)(ws + 0);              // 33,554,432 B  (aliased as y after attention)
  short* LT = (short*)(ws + 33554432);       //  2,097,152 B
  short* WT = (short*)(ws + 35651584);       //  4,194,304 B
  short* xl = (short*)(ws + 39845888);       //  6,291,456 B
  short* yl = (short*)(ws + 46137344);       //  2,097,152 B
  short* qb = (short*)(ws + 48234496);       // 33,554,432 B
  short* kb = (short*)(ws + 81788928);       // 33,554,432 B
  short* vT = (short*)(ws + 115343360);      // 33,554,432 B
  short* y  = xb;

  cast_x_kernel<<<16384, 256, 0, stream>>>(x, xb, 4194304L);
  prep_kernel<<<12288, 256, 0, stream>>>(left_w, diag, right_w, LT, WT);
  gemm_bt<<<dim3(64, 3), 256, 0, stream>>>(xb, LT, xl, 8192, 384, 2048);
  lori_gemm<<<dim3(64, 48), 256, 0, stream>>>(xb, xl, 384, WT, right_b, bias_p, 0, qb, kb, vT, nullptr);
  attn_kernel<<<dim3(16, 64), 256, 0, stream>>>(qb, kb, vT, y);
  gemm_bt<<<dim3(64, 1), 256, 0, stream>>>(y, LT + 3L * 128 * 2048, yl, 8192, 128, 2048);
  lori_gemm<<<dim3(64, 16), 256, 0, stream>>>(y, yl, 128, WT, right_b, bias_p, 3, nullptr, nullptr, nullptr, out);
}

// Round 3
// 570.451 us; speedup vs baseline: 1.5689x; 1.5689x over previous
//
#include <hip/hip_runtime.h>

typedef short bf16x8 __attribute__((ext_vector_type(8)));
typedef float f32x4  __attribute__((ext_vector_type(4)));

#define AS1 __attribute__((address_space(1)))
#define AS3 __attribute__((address_space(3)))

__device__ __forceinline__ void gload16(const void* g, void* l) {
  __builtin_amdgcn_global_load_lds((const AS1 void*)g, (AS3 void*)l, 16, 0, 0);
}

__device__ __forceinline__ short f2bf(float f) {
  union { float fv; unsigned u; } v; v.fv = f;
  unsigned r = v.u + 0x7fffu + ((v.u >> 16) & 1u);
  return (short)(r >> 16);
}

// in-place 16-lane max reduction step via ds_swizzle (xor pattern, 1 instr)
#define MAXSTEP(x, IMM) { int t_ = __builtin_amdgcn_ds_swizzle(__float_as_int(x), IMM); \
                          x = fmaxf(x, __int_as_float(t_)); }

// ---------------- cast x (fp32 -> bf16), 4 elems/thread ----------------
__global__ void cast_x_kernel(const float* __restrict__ x, short* __restrict__ xb, long n4) {
  long i = (long)blockIdx.x * 256 + threadIdx.x;
  if (i < n4) {
    float4 v = ((const float4*)x)[i];
    short4 s;
    s.x = f2bf(v.x); s.y = f2bf(v.y); s.z = f2bf(v.z); s.w = f2bf(v.w);
    ((short4*)xb)[i] = s;
  }
}

// ---------------- weight prep ----------------
__global__ void prep_kernel(const float* __restrict__ left_w, const float* __restrict__ diag,
                            const float* __restrict__ right_w,
                            short* __restrict__ LT, short* __restrict__ WT) {
  long idx = (long)blockIdx.x * 256 + threadIdx.x;
  const long LTN = 4L * 128 * 2048;
  const long WTN = 4L * 16 * 128 * 256;
  if (idx < LTN) {
    LT[idx] = f2bf(left_w[idx]);
  } else if (idx < LTN + WTN) {
    long j = idx - LTN;
    int d = (int)(j & 255);
    long rest = j >> 8;
    int e = (int)(rest & 127);
    long gi = rest >> 7;
    int i = (int)(gi >> 4), n = (int)(gi & 15);
    float v;
    if (d < 128) v = diag[(gi * 128 + d) * 128 + e];
    else         v = right_w[((long)i * 2048 + n * 128 + e) * 128 + (d - 128)];
    WT[j] = f2bf(v);
  }
}

// ---------------- 128x128-tile GEMM (XOR-swizzled LDS): C = A @ BT^T ----------------
__global__ __launch_bounds__(256) void gemm_bt(const short* __restrict__ A, const short* __restrict__ BT,
                                               short* __restrict__ C, int M, int N, int K) {
  __shared__ __align__(16) short As[128 * 64];
  __shared__ __align__(16) short Bs[128 * 64];
  int tid = threadIdx.x, w = tid >> 6, lane = tid & 63;
  int m0 = blockIdx.x * 128, n0 = blockIdx.y * 128;
  int wm = (w >> 1) * 64, wn = (w & 1) * 64;
  int quad = lane >> 4, l16 = lane & 15;
  int srow = lane >> 3;
  int schunk = ((lane & 7) ^ srow) * 8;   // XOR-swizzled source chunk
  f32x4 acc[4][4] = {};
  for (int k0 = 0; k0 < K; k0 += 64) {
    for (int p = 0; p < 4; ++p) {
      int r = p * 32 + w * 8 + srow;
      gload16(&A[(long)(m0 + r) * K + k0 + schunk], &As[(p * 32 + w * 8) * 64]);
      gload16(&BT[(long)(n0 + r) * K + k0 + schunk], &Bs[(p * 32 + w * 8) * 64]);
    }
    __syncthreads();
#pragma unroll
    for (int kk = 0; kk < 2; ++kk) {
      int c = (((kk * 4 + quad) ^ (l16 & 7)) * 8);
      bf16x8 a[4], b[4];
#pragma unroll
      for (int t = 0; t < 4; ++t) a[t] = *(const bf16x8*)&As[(wm + t * 16 + l16) * 64 + c];
#pragma unroll
      for (int t = 0; t < 4; ++t) b[t] = *(const bf16x8*)&Bs[(wn + t * 16 + l16) * 64 + c];
#pragma unroll
      for (int mt = 0; mt < 4; ++mt)
#pragma unroll
        for (int nt = 0; nt < 4; ++nt)
          acc[mt][nt] = __builtin_amdgcn_mfma_f32_16x16x32_bf16(a[mt], b[nt], acc[mt][nt], 0, 0, 0);
    }
    __syncthreads();
  }
#pragma unroll
  for (int mt = 0; mt < 4; ++mt)
#pragma unroll
    for (int nt = 0; nt < 4; ++nt)
#pragma unroll
      for (int r = 0; r < 4; ++r) {
        int m = m0 + wm + mt * 16 + quad * 4 + r;
        int n = n0 + wn + nt * 16 + l16;
        C[(long)m * N + n] = f2bf(acc[mt][nt][r]);
      }
}

// ---------------- grouped lori GEMM (XOR-swizzled LDS) ----------------
__global__ __launch_bounds__(256) void lori_gemm(const short* __restrict__ tok, const short* __restrict__ rnk,
                                                 int rstride, const short* __restrict__ WT,
                                                 const float* __restrict__ rb, const float* __restrict__ bp,
                                                 int i_base, short* __restrict__ qb, short* __restrict__ kb,
                                                 short* __restrict__ vT, float* __restrict__ out) {
  __shared__ __align__(16) short As[128 * 64];
  __shared__ __align__(16) short Bs[128 * 64];
  int tid = threadIdx.x, w = tid >> 6, lane = tid & 63;
  int i = i_base + (blockIdx.y >> 4);
  int n = blockIdx.y & 15;
  int t0 = blockIdx.x * 128;
  int co = (i < 3) ? i * 128 : 0;
  const short* WTn = WT + (long)(i * 16 + n) * 128 * 256;
  int wm = (w >> 1) * 64, wn = (w & 1) * 64;
  int quad = lane >> 4, l16 = lane & 15;
  int srow = lane >> 3;
  int schunk = ((lane & 7) ^ srow) * 8;
  f32x4 acc[4][4] = {};
#pragma unroll
  for (int kt = 0; kt < 4; ++kt) {
    for (int p = 0; p < 4; ++p) {
      int r = p * 32 + w * 8 + srow;
      const short* ga;
      if (kt < 2) ga = &tok[(long)(t0 + r) * 2048 + n * 128 + kt * 64 + schunk];
      else        ga = &rnk[(long)(t0 + r) * rstride + co + (kt - 2) * 64 + schunk];
      gload16(ga, &As[(p * 32 + w * 8) * 64]);
      gload16(&WTn[r * 256 + kt * 64 + schunk], &Bs[(p * 32 + w * 8) * 64]);
    }
    __syncthreads();
#pragma unroll
    for (int kk = 0; kk < 2; ++kk) {
      int c = (((kk * 4 + quad) ^ (l16 & 7)) * 8);
      bf16x8 a[4], b[4];
#pragma unroll
      for (int t = 0; t < 4; ++t) a[t] = *(const bf16x8*)&As[(wm + t * 16 + l16) * 64 + c];
#pragma unroll
      for (int t = 0; t < 4; ++t) b[t] = *(const bf16x8*)&Bs[(wn + t * 16 + l16) * 64 + c];
#pragma unroll
      for (int mt = 0; mt < 4; ++mt)
#pragma unroll
        for (int nt = 0; nt < 4; ++nt)
          acc[mt][nt] = __builtin_amdgcn_mfma_f32_16x16x32_bf16(a[mt], b[nt], acc[mt][nt], 0, 0, 0);
    }
    __syncthreads();
  }
  int b = t0 >> 11;
  int tl0 = t0 & 2047;
  const float QSC = 0.08838834764831845f * 1.4426950408889634f;  // 1/sqrt(128) * log2(e)
#pragma unroll
  for (int mt = 0; mt < 4; ++mt) {
#pragma unroll
    for (int nt = 0; nt < 4; ++nt) {
      int e = wn + nt * 16 + l16;
      int c = n * 128 + e;
      float bias = rb[i * 2048 + c] + bp[i * 2048 + c];
      int tl = tl0 + wm + mt * 16 + quad * 4;
      if (i == 0) {
#pragma unroll
        for (int r = 0; r < 4; ++r)
          qb[((long)(b * 16 + n) * 2048 + tl + r) * 128 + e] = f2bf((acc[mt][nt][r] + bias) * QSC);
      } else if (i == 1) {
#pragma unroll
        for (int r = 0; r < 4; ++r)
          kb[((long)(b * 16 + n) * 2048 + tl + r) * 128 + e] = f2bf(acc[mt][nt][r] + bias);
      } else if (i == 2) {
        short4 s4;
        s4.x = f2bf(acc[mt][nt][0] + bias);
        s4.y = f2bf(acc[mt][nt][1] + bias);
        s4.z = f2bf(acc[mt][nt][2] + bias);
        s4.w = f2bf(acc[mt][nt][3] + bias);
        *(short4*)&vT[((long)(b * 16 + n) * 128 + e) * 2048 + tl] = s4;
      } else {
#pragma unroll
        for (int r = 0; r < 4; ++r)
          out[(long)(t0 + wm + mt * 16 + quad * 4 + r) * 2048 + c] = acc[mt][nt][r] + bias;
      }
    }
  }
}

// ---------------- flash attention v3: double-buffered K/V prefetch + XCD-local scheduling ----------------
// qb,kb: [bh][t][d] bf16 (q pre-scaled by log2e/sqrt(128)); vT: [bh][d][t]; y: [b][t][h*128+d]
// grid: 1024 blocks 1D. id%8 = XCD (HW round-robin); all 16 q-tiles of a bh land on one XCD.
__global__ __launch_bounds__(256) void attn_kernel(const short* __restrict__ qb, const short* __restrict__ kb,
                                                   const short* __restrict__ vT, short* __restrict__ y) {
  __shared__ __align__(16) short ks[2][64 * 128];   // K tiles, 16-chunk XOR swizzle per row
  __shared__ __align__(16) short vs[2][128 * 64];   // V^T tiles, 8-chunk XOR swizzle per row
  __shared__ __align__(16) short ps[4][32 * 64];    // P per wave, 8-chunk XOR swizzle per row
  int tid = threadIdx.x, w = tid >> 6, lane = tid & 63;
  int id = blockIdx.x;
  int xcd = id & 7, slot = id >> 3;
  int qt = 15 - (slot & 15);          // long q-tiles first
  int bh = xcd + 8 * (slot >> 4);     // 8 bh per XCD, q-tiles of one bh co-resident
  int b = bh >> 4, h = bh & 15;
  int quad = lane >> 4, l16 = lane & 15;

  // Q fragments direct global->VGPR (A-layout): rows w*32 + mt*16 + l16
  bf16x8 aq[2][4];
#pragma unroll
  for (int mt = 0; mt < 2; ++mt)
#pragma unroll
    for (int kk = 0; kk < 4; ++kk)
      aq[mt][kk] = *(const bf16x8*)&qb[((long)bh * 2048 + qt * 128 + w * 32 + mt * 16 + l16) * 128 + kk * 32 + quad * 8];

  f32x4 O[2][8] = {};
  f32x4 Lacc[2] = {};
  f32x4 mst[2];
#pragma unroll
  for (int mt = 0; mt < 2; ++mt) mst[mt] = f32x4{-3.0e38f, -3.0e38f, -3.0e38f, -3.0e38f};
  const bf16x8 ones = {(short)0x3F80, (short)0x3F80, (short)0x3F80, (short)0x3F80,
                       (short)0x3F80, (short)0x3F80, (short)0x3F80, (short)0x3F80};
  short* psw = &ps[w][0];

  // staging lane constants
  int kq = lane >> 4;                       // 0..3
  int kchunk = l16 ^ (w * 4 + kq);          // row&15 = w*4+kq
  int vrow8 = lane >> 3;                    // 0..7
  int vchunk = (lane & 7) ^ vrow8;          // row&7 = vrow8

  const short* kbase = kb + (long)bh * 2048 * 128;
  const short* vbase = vT + (long)bh * 128 * 2048;

#define STAGE(JT, BUF) {                                                              \
    for (int p = 0; p < 4; ++p) {                                                     \
      int r = p * 16 + w * 4 + kq;                                                    \
      gload16(&kbase[((long)((JT) * 64 + r)) * 128 + kchunk * 8], &ks[BUF][(p * 16 + w * 4) * 128]); \
      int r2 = p * 32 + w * 8 + vrow8;                                                \
      gload16(&vbase[(long)r2 * 2048 + (JT) * 64 + vchunk * 8], &vs[BUF][(p * 32 + w * 8) * 64]);    \
    }                                                                                 \
  }

  int jmax = 2 * qt + 1;
  STAGE(0, 0)
  __syncthreads();
  for (int jt = 0; jt <= jmax; ++jt) {
    int cur = jt & 1;
    if (jt < jmax) STAGE(jt + 1, cur ^ 1)   // prefetch overlaps compute below

    bool active = !(jt == jmax && w < 2);   // waves 0,1 fully masked on the last diagonal sub-tile
    if (active) {
      // S = Q @ K^T  (wave: 32 rows x 64 keys)
      f32x4 s[2][4] = {};
#pragma unroll
      for (int nt = 0; nt < 4; ++nt)
#pragma unroll
        for (int kk = 0; kk < 4; ++kk) {
          bf16x8 bk = *(const bf16x8*)&ks[cur][(nt * 16 + l16) * 128 + (((kk * 4 + quad) ^ l16) * 8)];
          s[0][nt] = __builtin_amdgcn_mfma_f32_16x16x32_bf16(aq[0][kk], bk, s[0][nt], 0, 0, 0);
          s[1][nt] = __builtin_amdgcn_mfma_f32_16x16x32_bf16(aq[1][kk], bk, s[1][nt], 0, 0, 0);
        }
      if (jt >= 2 * qt) {
#pragma unroll
        for (int mt = 0; mt < 2; ++mt)
#pragma unroll
          for (int nt = 0; nt < 4; ++nt) {
            int key = jt * 64 + nt * 16 + l16;
#pragma unroll
            for (int r = 0; r < 4; ++r) {
              int rowg = qt * 128 + w * 32 + mt * 16 + quad * 4 + r;
              if (key > rowg) s[mt][nt][r] = -3.0e38f;
            }
          }
      }
#pragma unroll
      for (int mt = 0; mt < 2; ++mt) {
        // running max + rescale factor (base-2 domain)
        f32x4 alv;
#pragma unroll
        for (int r = 0; r < 4; ++r) {
          float mx = fmaxf(fmaxf(s[mt][0][r], s[mt][1][r]), fmaxf(s[mt][2][r], s[mt][3][r]));
          MAXSTEP(mx, 0x041F); MAXSTEP(mx, 0x081F); MAXSTEP(mx, 0x101F); MAXSTEP(mx, 0x201F);
          float nm = fmaxf(mst[mt][r], mx);
          alv[r] = __builtin_amdgcn_exp2f(mst[mt][r] - nm);
          mst[mt][r] = nm;
        }
        Lacc[mt] *= alv;
#pragma unroll
        for (int dt = 0; dt < 8; ++dt) O[mt][dt] *= alv;
        // P = exp2(S - m), write to swizzled LDS (C-layout -> A-layout)
#pragma unroll
        for (int nt = 0; nt < 4; ++nt)
#pragma unroll
          for (int r = 0; r < 4; ++r) {
            float p = __builtin_amdgcn_exp2f(s[mt][nt][r] - mst[mt][r]);
            int row = mt * 16 + quad * 4 + r;
            int cw = (nt * 2 + (l16 >> 3)) ^ (row & 7);
            psw[row * 64 + cw * 8 + (l16 & 7)] = f2bf(p);
          }
        // O += P @ V ; Lacc += P @ 1
#pragma unroll
        for (int kk = 0; kk < 2; ++kk) {
          bf16x8 ap = *(const bf16x8*)&psw[(mt * 16 + l16) * 64 + (((kk * 4 + quad) ^ (l16 & 7)) * 8)];
#pragma unroll
          for (int dt = 0; dt < 8; ++dt) {
            bf16x8 bv = *(const bf16x8*)&vs[cur][(dt * 16 + l16) * 64 + (((kk * 4 + quad) ^ (l16 & 7)) * 8)];
            O[mt][dt] = __builtin_amdgcn_mfma_f32_16x16x32_bf16(ap, bv, O[mt][dt], 0, 0, 0);
          }
          Lacc[mt] = __builtin_amdgcn_mfma_f32_16x16x32_bf16(ap, ones, Lacc[mt], 0, 0, 0);
        }
      }
    }
    __syncthreads();
  }
#undef STAGE
  // epilogue: y = O / l
#pragma unroll
  for (int mt = 0; mt < 2; ++mt) {
    f32x4 inv;
#pragma unroll
    for (int r = 0; r < 4; ++r) inv[r] = __builtin_amdgcn_rcpf(Lacc[mt][r]);
#pragma unroll
    for (int dt = 0; dt < 8; ++dt)
#pragma unroll
      for (int r = 0; r < 4; ++r) {
        int t = qt * 128 + w * 32 + mt * 16 + quad * 4 + r;
        y[((long)(b * 2048 + t)) * 2048 + h * 128 + dt * 16 + l16] = f2bf(O[mt][dt][r] * inv[r]);
      }
  }
}

extern "C" void kernel_launch(void* const* d_in, const int* in_sizes, int n_in,
                              void* d_out, int out_size, void* d_ws, size_t ws_size,
                              hipStream_t stream) {
  const float* x       = (const float*)d_in[0];
  const float* diag    = (const float*)d_in[1];
  const float* left_w  = (const float*)d_in[2];
  const float* right_w = (const float*)d_in[3];
  const float* right_b = (const float*)d_in[4];
  const float* bias_p  = (const float*)d_in[5];
  float* out = (float*)d_out;

  char* ws = (char*)d_ws;
  short* xb = (short*)(ws + 0);              // 33,554,432 B  (aliased as y after attention)
  short* LT = (short*)(ws + 33554432);       //  2,097,152 B
  short* WT = (short*)(ws + 35651584);       //  4,194,304 B
  short* xl = (short*)(ws + 39845888);       //  6,291,456 B
  short* yl = (short*)(ws + 46137344);       //  2,097,152 B
  short* qb = (short*)(ws + 48234496);       // 33,554,432 B
  short* kb = (short*)(ws + 81788928);       // 33,554,432 B
  short* vT = (short*)(ws + 115343360);      // 33,554,432 B
  short* y  = xb;

  cast_x_kernel<<<16384, 256, 0, stream>>>(x, xb, 4194304L);
  prep_kernel<<<12288, 256, 0, stream>>>(left_w, diag, right_w, LT, WT);
  gemm_bt<<<dim3(64, 3), 256, 0, stream>>>(xb, LT, xl, 8192, 384, 2048);
  lori_gemm<<<dim3(64, 48), 256, 0, stream>>>(xb, xl, 384, WT, right_b, bias_p, 0, qb, kb, vT, nullptr);
  attn_kernel<<<dim3(1024), 256, 0, stream>>>(qb, kb, vT, y);
  gemm_bt<<<dim3(64, 1), 256, 0, stream>>>(y, LT + 3L * 128 * 2048, yl, 8192, 128, 2048);
  lori_gemm<<<dim3(64, 16), 256, 0, stream>>>(y, yl, 128, WT, right_b, bias_p, 3, nullptr, nullptr, nullptr, out);
}